// Round 6
// baseline (59.267 us; speedup 1.0000x reference)
//
#include <hip/hip_runtime.h>

// Problem constants (from setup_inputs): B=16, C=320, H=W=64, G=5, Cg=64
#define BATCH 16
#define CHAN  320
#define HH    64
#define WW    64
#define PLANE (HH*WW)            // 4096
#define NGRP  5
#define CG    64                 // CHAN / NGRP
#define CPB   4                  // channels per block in k_shift_blend

// Static device scratch (module-load allocated; avoids any dependence on
// ws_size). Fully overwritten before being read on every kernel_launch call.
__device__ float g_em[BATCH * PLANE];   // channel SUM of edge_guidance
__device__ float g_w0[BATCH * PLANE];   // softmax weight for the H-shift term

// ---------------------------------------------------------------------------
// Kernel 1: g_em[b,r,q] = sum_c edge_guidance[b,c,r,q]
// grid = B*H blocks (1024); block = 256 = 64 q-lanes x 4 channel-chunks of 80
// ---------------------------------------------------------------------------
__global__ void k_reduce_mean(const float* __restrict__ eg)
{
    __shared__ float red[256];
    const int bid = blockIdx.x;           // b*64 + r
    const int b = bid >> 6;
    const int r = bid & 63;
    const int q   = threadIdx.x & 63;
    const int grp = threadIdx.x >> 6;     // 0..3, each owns 80 channels

    const float* p = eg + (((size_t)b * CHAN + (size_t)grp * 80) * PLANE) + r * WW + q;
    float s = 0.f;
#pragma unroll 8
    for (int c = 0; c < 80; ++c)
        s += p[(size_t)c * PLANE];

    red[threadIdx.x] = s;
    __syncthreads();
    if (grp == 0) {
        // store channel SUM; the 1/320 scale is folded into kernel 2's load
        g_em[(size_t)bid * 64 + q] = red[q] + red[q + 64] + red[q + 128] + red[q + 192];
    }
}

// ---------------------------------------------------------------------------
// Kernel 2: fused conv1(1->16,3x3)+relu -> conv2(16->2,3x3) -> softmax -> w0
// grid = B*16 blocks (one 16x16 output tile each); block = 256
// em tile staged 20x20 (halo 2), h computed per input-channel on 18x18 (halo 1)
// h is ZERO outside the 64x64 image (reference zero-pads h for conv2).
// ---------------------------------------------------------------------------
__global__ void k_conv_dir(const float* __restrict__ w1, const float* __restrict__ b1,
                           const float* __restrict__ w2, const float* __restrict__ b2)
{
    __shared__ float sem[20][20];
    __shared__ float shh[18][18];
    __shared__ float sw1[16][9];
    __shared__ float sb1[16];
    __shared__ float sw2[2][16][9];
    __shared__ float sb2[2];

    const int bid = blockIdx.x;
    const int b  = bid >> 4;
    const int t  = bid & 15;
    const int r0 = (t >> 2) * 16;
    const int q0 = (t & 3) * 16;
    const int tid = threadIdx.x;

    if (tid < 144) sw1[tid / 9][tid % 9] = w1[tid];
    if (tid < 16)  sb1[tid] = b1[tid];
    // 288 elements > 256 threads: strided (fixed round-3 bug)
    for (int i = tid; i < 288; i += 256) ((float*)sw2)[i] = w2[i];
    if (tid < 2)   sb2[tid] = b2[tid];

    const float scale = 1.0f / (float)CHAN;
    for (int i = tid; i < 400; i += 256) {
        const int lr = i / 20, lq = i % 20;
        const int r = r0 + lr - 2, q = q0 + lq - 2;
        float v = 0.f;
        if ((unsigned)r < HH && (unsigned)q < WW)
            v = g_em[((size_t)b * HH + r) * WW + q] * scale;
        sem[lr][lq] = v;
    }
    __syncthreads();

    const int lr = tid >> 4;   // output pixel within 16x16 tile
    const int lq = tid & 15;
    float l0 = sb2[0];
    float l1 = sb2[1];

    for (int i = 0; i < 16; ++i) {
        // h_i on the 18x18 halo region; zero outside the image
        for (int p = tid; p < 324; p += 256) {
            const int hr = p / 18, hq = p % 18;
            const int gr = r0 - 1 + hr, gq = q0 - 1 + hq;
            float acc = 0.f;
            if ((unsigned)gr < HH && (unsigned)gq < WW) {
                acc = sb1[i];
#pragma unroll
                for (int dr = 0; dr < 3; ++dr)
#pragma unroll
                    for (int dq = 0; dq < 3; ++dq)
                        acc += sem[hr + dr][hq + dq] * sw1[i][dr * 3 + dq];
                acc = fmaxf(acc, 0.f);
            }
            shh[hr][hq] = acc;
        }
        __syncthreads();
#pragma unroll
        for (int dr = 0; dr < 3; ++dr)
#pragma unroll
            for (int dq = 0; dq < 3; ++dq) {
                const float hv = shh[lr + dr][lq + dq];
                l0 += hv * sw2[0][i][dr * 3 + dq];
                l1 += hv * sw2[1][i][dr * 3 + dq];
            }
        __syncthreads();
    }

    const float m  = fmaxf(l0, l1);
    const float e0 = expf(l0 - m);
    const float e1 = expf(l1 - m);
    const float w0v = e0 / (e0 + e1);
    g_w0[((size_t)b * HH + (r0 + lr)) * WW + (q0 + lq)] = w0v;
}

// ---------------------------------------------------------------------------
// Kernel 3: out[b,c,r,q] = w0[b,r,q]*X(r-sh[g],q) + (1-w0[b,r,q])*X(r,q-sw[g])
// Channel-batched: one block = CPB=4 consecutive channel planes of one batch.
// grid = B*(CHAN/CPB) = 1280 blocks (exactly 5/CU); block = 256 threads.
// w0 plane held in 16 VGPRs, reused across the 4 planes (w0 traffic /4,
// per-block work x4, 16 independent load->blend->store chains for MLP).
// W-shift (|sw|<=2, uniform): own float4 + one aligned neighbor float4,
// component-select under uniform branch. Clamped offsets only feed components
// zeroed by the q==0 / q==60 edge predicates; no OOB.
// ---------------------------------------------------------------------------
__global__ void k_shift_blend(const float* __restrict__ x,
                              const int* __restrict__ sh_arr, const int* __restrict__ sw_arr,
                              float* __restrict__ out)
{
    const int bid = blockIdx.x;            // b*(CHAN/CPB) + cb
    const int nb  = CHAN / CPB;            // 80
    const int cb  = bid % nb;
    const int b   = bid / nb;
    const int c0  = cb * CPB;
    const int g   = c0 >> 6;               // CPB divides 64 -> uniform group
    const int sh  = sh_arr[g];
    const int sw  = sw_arr[g];

    const float* wp = g_w0 + (size_t)b * PLANE;

    // w0: 4 float4 per thread, loaded once
    float4 wv[4];
#pragma unroll
    for (int j = 0; j < 4; ++j)
        wv[j] = ((const float4*)wp)[threadIdx.x + j * 256];

#pragma unroll
    for (int cc = 0; cc < CPB; ++cc) {
        const float* xp = x   + ((size_t)b * CHAN + c0 + cc) * PLANE;
        float*       op = out + ((size_t)b * CHAN + c0 + cc) * PLANE;

#pragma unroll
        for (int j = 0; j < 4; ++j) {
            const int p4 = threadIdx.x + j * 256;   // float4 index (0..1023)
            const int r  = p4 >> 4;
            const int q4 = p4 & 15;
            const int q  = q4 * 4;
            const int base = r * WW + q;

            const float4 xv = ((const float4*)xp)[p4];

            // H-shift: aligned float4 from row (r - sh); plane is L1-resident
            float4 xh = make_float4(0.f, 0.f, 0.f, 0.f);
            const int rs = r - sh;
            if ((unsigned)rs < HH)
                xh = *(const float4*)(xp + rs * WW + q);

            // W-shift: own float4 + one aligned neighbor, uniform select
            float xw0, xw1, xw2, xw3;
            if (sw == 0) {
                xw0 = xv.x; xw1 = xv.y; xw2 = xv.z; xw3 = xv.w;
            } else if (sw > 0) {
                int off = base - 4; if (off < 0) off = 0;       // clamp: masked comps only
                const float4 xm = *(const float4*)(xp + off);   // x[r, q-4..q-1]
                if (sw == 1) { xw0 = xm.w; xw1 = xv.x; xw2 = xv.y; xw3 = xv.z; }
                else         { xw0 = xm.z; xw1 = xm.w; xw2 = xv.x; xw3 = xv.y; }
                if (q == 0) { xw0 = 0.f; if (sw == 2) xw1 = 0.f; }  // qs < 0
            } else {
                int off = base + 4; if (off > PLANE - 4) off = PLANE - 4;
                const float4 xr = *(const float4*)(xp + off);   // x[r, q+4..q+7]
                if (sw == -1) { xw0 = xv.y; xw1 = xv.z; xw2 = xv.w; xw3 = xr.x; }
                else          { xw0 = xv.z; xw1 = xv.w; xw2 = xr.x; xw3 = xr.y; }
                if (q == WW - 4) { xw3 = 0.f; if (sw == -2) xw2 = 0.f; }  // qs >= 64
            }

            float4 o;
            o.x = xw0 + wv[j].x * (xh.x - xw0);
            o.y = xw1 + wv[j].y * (xh.y - xw1);
            o.z = xw2 + wv[j].z * (xh.z - xw2);
            o.w = xw3 + wv[j].w * (xh.w - xw3);
            ((float4*)op)[p4] = o;
        }
    }
}

extern "C" void kernel_launch(void* const* d_in, const int* in_sizes, int n_in,
                              void* d_out, int out_size, void* d_ws, size_t ws_size,
                              hipStream_t stream)
{
    const float* x   = (const float*)d_in[0];
    const float* eg  = (const float*)d_in[1];
    const float* w1  = (const float*)d_in[2];
    const float* b1  = (const float*)d_in[3];
    const float* w2  = (const float*)d_in[4];
    const float* b2  = (const float*)d_in[5];
    const int*   shh = (const int*)d_in[6];
    const int*   shw = (const int*)d_in[7];
    float* out = (float*)d_out;

    k_reduce_mean<<<BATCH * HH, 256, 0, stream>>>(eg);
    k_conv_dir<<<BATCH * 16, 256, 0, stream>>>(w1, b1, w2, b2);
    k_shift_blend<<<BATCH * (CHAN / CPB), 256, 0, stream>>>(x, shh, shw, out);
}

// Round 8
// 58.019 us; speedup vs baseline: 1.0215x; 1.0215x over previous
//
#include <hip/hip_runtime.h>

// Problem constants (from setup_inputs): B=16, C=320, H=W=64, G=5, Cg=64
#define BATCH 16
#define CHAN  320
#define HH    64
#define WW    64
#define PLANE (HH*WW)            // 4096
#define NGRP  5
#define CG    64                 // CHAN / NGRP
#define CPB   2                  // channels per block in k_shift_blend

typedef float vfloat4 __attribute__((ext_vector_type(4)));  // clang-native for nt-store

// Static device scratch (module-load allocated; avoids any dependence on
// ws_size). Fully overwritten before being read on every kernel_launch call.
__device__ float g_em[BATCH * PLANE];   // channel SUM of edge_guidance
__device__ float g_w0[BATCH * PLANE];   // softmax weight for the H-shift term

// ---------------------------------------------------------------------------
// Kernel 1: g_em[b,r,q] = sum_c edge_guidance[b,c,r,q]
// grid = B*H blocks (1024); block = 256 = 64 q-lanes x 4 channel-chunks of 80
// ---------------------------------------------------------------------------
__global__ void k_reduce_mean(const float* __restrict__ eg)
{
    __shared__ float red[256];
    const int bid = blockIdx.x;           // b*64 + r
    const int b = bid >> 6;
    const int r = bid & 63;
    const int q   = threadIdx.x & 63;
    const int grp = threadIdx.x >> 6;     // 0..3, each owns 80 channels

    const float* p = eg + (((size_t)b * CHAN + (size_t)grp * 80) * PLANE) + r * WW + q;
    float s = 0.f;
#pragma unroll 8
    for (int c = 0; c < 80; ++c)
        s += p[(size_t)c * PLANE];

    red[threadIdx.x] = s;
    __syncthreads();
    if (grp == 0) {
        // store channel SUM; the 1/320 scale is folded into kernel 2's load
        g_em[(size_t)bid * 64 + q] = red[q] + red[q + 64] + red[q + 128] + red[q + 192];
    }
}

// ---------------------------------------------------------------------------
// Kernel 2: fused conv1(1->16,3x3)+relu -> conv2(16->2,3x3) -> softmax -> w0
// grid = B*16 blocks (one 16x16 output tile each); block = 256
// em tile staged 20x20 (halo 2), h computed per input-channel on 18x18 (halo 1)
// h is ZERO outside the 64x64 image (reference zero-pads h for conv2).
// ---------------------------------------------------------------------------
__global__ void k_conv_dir(const float* __restrict__ w1, const float* __restrict__ b1,
                           const float* __restrict__ w2, const float* __restrict__ b2)
{
    __shared__ float sem[20][20];
    __shared__ float shh[18][18];
    __shared__ float sw1[16][9];
    __shared__ float sb1[16];
    __shared__ float sw2[2][16][9];
    __shared__ float sb2[2];

    const int bid = blockIdx.x;
    const int b  = bid >> 4;
    const int t  = bid & 15;
    const int r0 = (t >> 2) * 16;
    const int q0 = (t & 3) * 16;
    const int tid = threadIdx.x;

    if (tid < 144) sw1[tid / 9][tid % 9] = w1[tid];
    if (tid < 16)  sb1[tid] = b1[tid];
    // 288 elements > 256 threads: strided (fixed round-3 bug)
    for (int i = tid; i < 288; i += 256) ((float*)sw2)[i] = w2[i];
    if (tid < 2)   sb2[tid] = b2[tid];

    const float scale = 1.0f / (float)CHAN;
    for (int i = tid; i < 400; i += 256) {
        const int lr = i / 20, lq = i % 20;
        const int r = r0 + lr - 2, q = q0 + lq - 2;
        float v = 0.f;
        if ((unsigned)r < HH && (unsigned)q < WW)
            v = g_em[((size_t)b * HH + r) * WW + q] * scale;
        sem[lr][lq] = v;
    }
    __syncthreads();

    const int lr = tid >> 4;   // output pixel within 16x16 tile
    const int lq = tid & 15;
    float l0 = sb2[0];
    float l1 = sb2[1];

    for (int i = 0; i < 16; ++i) {
        // h_i on the 18x18 halo region; zero outside the image
        for (int p = tid; p < 324; p += 256) {
            const int hr = p / 18, hq = p % 18;
            const int gr = r0 - 1 + hr, gq = q0 - 1 + hq;
            float acc = 0.f;
            if ((unsigned)gr < HH && (unsigned)gq < WW) {
                acc = sb1[i];
#pragma unroll
                for (int dr = 0; dr < 3; ++dr)
#pragma unroll
                    for (int dq = 0; dq < 3; ++dq)
                        acc += sem[hr + dr][hq + dq] * sw1[i][dr * 3 + dq];
                acc = fmaxf(acc, 0.f);
            }
            shh[hr][hq] = acc;
        }
        __syncthreads();
#pragma unroll
        for (int dr = 0; dr < 3; ++dr)
#pragma unroll
            for (int dq = 0; dq < 3; ++dq) {
                const float hv = shh[lr + dr][lq + dq];
                l0 += hv * sw2[0][i][dr * 3 + dq];
                l1 += hv * sw2[1][i][dr * 3 + dq];
            }
        __syncthreads();
    }

    const float m  = fmaxf(l0, l1);
    const float e0 = expf(l0 - m);
    const float e1 = expf(l1 - m);
    const float w0v = e0 / (e0 + e1);
    g_w0[((size_t)b * HH + (r0 + lr)) * WW + (q0 + lq)] = w0v;
}

// ---------------------------------------------------------------------------
// Kernel 3: out[b,c,r,q] = w0[b,r,q]*X(r-sh[g],q) + (1-w0[b,r,q])*X(r,q-sw[g])
// Latency-hiding version: the CPB=2 x-planes are staged into LDS via
// __builtin_amdgcn_global_load_lds (width 16) -- 8 fire-and-forget 1KB/wave
// DMA loads per thread, no VGPR round-trip, deep MLP. __syncthreads drains
// vmcnt. Compute then reads LDS (aligned b128 only) and streams the output
// with nontemporal stores (write-once data; keeps L2/L3 for x).
// grid = B*(CHAN/CPB) = 2560 blocks; block = 256; LDS 32 KB -> 5 blocks/CU.
// ---------------------------------------------------------------------------
__global__ __launch_bounds__(256) void k_shift_blend(
        const float* __restrict__ x,
        const int* __restrict__ sh_arr, const int* __restrict__ sw_arr,
        float* __restrict__ out)
{
    __shared__ float sx[CPB * PLANE];      // 2 x 16 KB = 32 KB

    const int tid  = threadIdx.x;
    const int lane = tid & 63;
    const int wave = tid >> 6;             // 0..3

    const int bid = blockIdx.x;            // b*(CHAN/CPB) + cb
    const int nb  = CHAN / CPB;            // 160
    const int cb  = bid % nb;
    const int b   = bid / nb;
    const int c0  = cb * CPB;
    const int g   = c0 >> 6;               // CPB divides 64 -> uniform group
    const int sh  = sh_arr[g];
    const int sw  = sw_arr[g];

    // --- stage CPB planes (32 KB) into LDS: 32 chunks of 1 KB, 8 per wave ---
    const char* gbase = (const char*)(x + ((size_t)b * CHAN + c0) * PLANE);
#pragma unroll
    for (int i = 0; i < 8; ++i) {
        const int byte_off = (wave * 8 + i) * 1024 + lane * 16;
        __builtin_amdgcn_global_load_lds(
            (const __attribute__((address_space(1))) unsigned int*)(gbase + byte_off),
            (__attribute__((address_space(3))) unsigned int*)((char*)sx + (wave * 8 + i) * 1024),
            16, 0, 0);
    }

    // w0: 4 float4 per thread, loaded while the DMA is in flight (independent)
    const float* wp = g_w0 + (size_t)b * PLANE;
    float4 wv[4];
#pragma unroll
    for (int j = 0; j < 4; ++j)
        wv[j] = ((const float4*)wp)[tid + j * 256];

    __syncthreads();   // drains vmcnt(0): all LDS-DMA complete

#pragma unroll
    for (int cc = 0; cc < CPB; ++cc) {
        float* op = out + ((size_t)b * CHAN + c0 + cc) * PLANE;
        const float* sp = sx + cc * PLANE;

#pragma unroll
        for (int j = 0; j < 4; ++j) {
            const int p4 = tid + j * 256;   // float4 index (0..1023)
            const int r  = p4 >> 4;
            const int q4 = p4 & 15;
            const int q  = q4 * 4;
            const int base = r * WW + q;

            const float4 xv = *(const float4*)(sp + base);

            // H-shift: aligned float4 from LDS row (r - sh)
            float4 xh = make_float4(0.f, 0.f, 0.f, 0.f);
            const int rs = r - sh;
            if ((unsigned)rs < HH)
                xh = *(const float4*)(sp + rs * WW + q);

            // W-shift: own float4 + one aligned neighbor float4, uniform
            // select. Clamped offsets only feed components zeroed by the
            // q==0 / q==60 edge predicates; all accesses stay in-plane.
            float xw0, xw1, xw2, xw3;
            if (sw == 0) {
                xw0 = xv.x; xw1 = xv.y; xw2 = xv.z; xw3 = xv.w;
            } else if (sw > 0) {
                int off = base - 4; if (off < 0) off = 0;
                const float4 xm = *(const float4*)(sp + off);   // x[r, q-4..q-1]
                if (sw == 1) { xw0 = xm.w; xw1 = xv.x; xw2 = xv.y; xw3 = xv.z; }
                else         { xw0 = xm.z; xw1 = xm.w; xw2 = xv.x; xw3 = xv.y; }
                if (q == 0) { xw0 = 0.f; if (sw == 2) xw1 = 0.f; }
            } else {
                int off = base + 4; if (off > PLANE - 4) off = PLANE - 4;
                const float4 xr = *(const float4*)(sp + off);   // x[r, q+4..q+7]
                if (sw == -1) { xw0 = xv.y; xw1 = xv.z; xw2 = xv.w; xw3 = xr.x; }
                else          { xw0 = xv.z; xw1 = xv.w; xw2 = xr.x; xw3 = xr.y; }
                if (q == WW - 4) { xw3 = 0.f; if (sw == -2) xw2 = 0.f; }
            }

            vfloat4 o;
            o.x = xw0 + wv[j].x * (xh.x - xw0);
            o.y = xw1 + wv[j].y * (xh.y - xw1);
            o.z = xw2 + wv[j].z * (xh.z - xw2);
            o.w = xw3 + wv[j].w * (xh.w - xw3);
            __builtin_nontemporal_store(o, (vfloat4*)op + p4);
        }
    }
}

extern "C" void kernel_launch(void* const* d_in, const int* in_sizes, int n_in,
                              void* d_out, int out_size, void* d_ws, size_t ws_size,
                              hipStream_t stream)
{
    const float* x   = (const float*)d_in[0];
    const float* eg  = (const float*)d_in[1];
    const float* w1  = (const float*)d_in[2];
    const float* b1  = (const float*)d_in[3];
    const float* w2  = (const float*)d_in[4];
    const float* b2  = (const float*)d_in[5];
    const int*   shh = (const int*)d_in[6];
    const int*   shw = (const int*)d_in[7];
    float* out = (float*)d_out;

    k_reduce_mean<<<BATCH * HH, 256, 0, stream>>>(eg);
    k_conv_dir<<<BATCH * 16, 256, 0, stream>>>(w1, b1, w2, b2);
    k_shift_blend<<<BATCH * (CHAN / CPB), 256, 0, stream>>>(x, shh, shw, out);
}